// Round 8
// baseline (118.616 us; speedup 1.0000x reference)
//
#include <hip/hip_runtime.h>

// out[i,j] = (z[i,:] . w) * w[j] + bias[j], all f32.  S=65536, B=1024.
// Fused, one row per block. R8 changes vs R7:
//  - z loaded with __builtin_nontemporal_load (streaming hint): z has zero
//    reuse and was flooding L2, evicting the broadcast w (256 KB) that every
//    block re-reads -> w degraded from L2-hit to L3 round-trips.
//  - dot phase unroll-8 with 8 accumulator chains (R7's VGPR=24 shows the
//    compiler collapsed the intended MLP to ~2 loads in flight).

#define SDIM 65536
#define S4   16384     // float4 per row
#define BLK  512

typedef float floatx4 __attribute__((ext_vector_type(4)));

__device__ __forceinline__ float dot4(floatx4 a, floatx4 b) {
    return a.x * b.x + a.y * b.y + a.z * b.z + a.w * b.w;
}

__global__ __launch_bounds__(BLK) void fused_ntload_kernel(
    const float* __restrict__ z,
    const float* __restrict__ w,
    const float* __restrict__ bias,
    float* __restrict__ out)
{
    const int row = blockIdx.x;
    const floatx4* __restrict__ zrow =
        reinterpret_cast<const floatx4*>(z + (size_t)row * SDIM);
    const floatx4* __restrict__ w4 = reinterpret_cast<const floatx4*>(w);
    const floatx4* __restrict__ b4 = reinterpret_cast<const floatx4*>(bias);
    floatx4* __restrict__ orow =
        reinterpret_cast<floatx4*>(out + (size_t)row * SDIM);

    // ---- phase 1: dot, unroll 8, 16 loads in flight, 8 accum chains ----
    // 16384 f4 / 512 thr = 32 iters/thread -> 4 outer iterations.
    float a0 = 0.f, a1 = 0.f, a2 = 0.f, a3 = 0.f;
    float a4 = 0.f, a5 = 0.f, a6 = 0.f, a7 = 0.f;
    for (int i = threadIdx.x; i < S4; i += 8 * BLK) {
        floatx4 x0 = __builtin_nontemporal_load(&zrow[i]);
        floatx4 x1 = __builtin_nontemporal_load(&zrow[i + BLK]);
        floatx4 x2 = __builtin_nontemporal_load(&zrow[i + 2 * BLK]);
        floatx4 x3 = __builtin_nontemporal_load(&zrow[i + 3 * BLK]);
        floatx4 x4 = __builtin_nontemporal_load(&zrow[i + 4 * BLK]);
        floatx4 x5 = __builtin_nontemporal_load(&zrow[i + 5 * BLK]);
        floatx4 x6 = __builtin_nontemporal_load(&zrow[i + 6 * BLK]);
        floatx4 x7 = __builtin_nontemporal_load(&zrow[i + 7 * BLK]);
        floatx4 y0 = w4[i];
        floatx4 y1 = w4[i + BLK];
        floatx4 y2 = w4[i + 2 * BLK];
        floatx4 y3 = w4[i + 3 * BLK];
        floatx4 y4 = w4[i + 4 * BLK];
        floatx4 y5 = w4[i + 5 * BLK];
        floatx4 y6 = w4[i + 6 * BLK];
        floatx4 y7 = w4[i + 7 * BLK];
        a0 += dot4(x0, y0); a1 += dot4(x1, y1);
        a2 += dot4(x2, y2); a3 += dot4(x3, y3);
        a4 += dot4(x4, y4); a5 += dot4(x5, y5);
        a6 += dot4(x6, y6); a7 += dot4(x7, y7);
    }
    float acc = ((a0 + a1) + (a2 + a3)) + ((a4 + a5) + (a6 + a7));

    #pragma unroll
    for (int off = 32; off > 0; off >>= 1)
        acc += __shfl_down(acc, off, 64);

    __shared__ float smem[BLK / 64];
    __shared__ float s_bcast;
    const int lane = threadIdx.x & 63;
    const int wid  = threadIdx.x >> 6;
    if (lane == 0) smem[wid] = acc;
    __syncthreads();
    if (threadIdx.x == 0) {
        float t = 0.f;
        #pragma unroll
        for (int i = 0; i < BLK / 64; ++i) t += smem[i];
        s_bcast = t;
    }
    __syncthreads();
    const float s = s_bcast;

    // ---- phase 2: out[row,:] = s*w + bias, unroll 4, NT stores ----
    for (int i = threadIdx.x; i < S4; i += 4 * BLK) {
        floatx4 y0 = w4[i];
        floatx4 y1 = w4[i + BLK];
        floatx4 y2 = w4[i + 2 * BLK];
        floatx4 y3 = w4[i + 3 * BLK];
        floatx4 c0 = b4[i];
        floatx4 c1 = b4[i + BLK];
        floatx4 c2 = b4[i + 2 * BLK];
        floatx4 c3 = b4[i + 3 * BLK];
        floatx4 r0, r1, r2, r3;
        r0.x = fmaf(s, y0.x, c0.x); r0.y = fmaf(s, y0.y, c0.y);
        r0.z = fmaf(s, y0.z, c0.z); r0.w = fmaf(s, y0.w, c0.w);
        r1.x = fmaf(s, y1.x, c1.x); r1.y = fmaf(s, y1.y, c1.y);
        r1.z = fmaf(s, y1.z, c1.z); r1.w = fmaf(s, y1.w, c1.w);
        r2.x = fmaf(s, y2.x, c2.x); r2.y = fmaf(s, y2.y, c2.y);
        r2.z = fmaf(s, y2.z, c2.z); r2.w = fmaf(s, y2.w, c2.w);
        r3.x = fmaf(s, y3.x, c3.x); r3.y = fmaf(s, y3.y, c3.y);
        r3.z = fmaf(s, y3.z, c3.z); r3.w = fmaf(s, y3.w, c3.w);
        __builtin_nontemporal_store(r0, &orow[i]);
        __builtin_nontemporal_store(r1, &orow[i + BLK]);
        __builtin_nontemporal_store(r2, &orow[i + 2 * BLK]);
        __builtin_nontemporal_store(r3, &orow[i + 3 * BLK]);
    }
}

extern "C" void kernel_launch(void* const* d_in, const int* in_sizes, int n_in,
                              void* d_out, int out_size, void* d_ws, size_t ws_size,
                              hipStream_t stream)
{
    const float* z    = (const float*)d_in[0];
    const float* w    = (const float*)d_in[1];  // (1,S,1) flat == (S,)
    const float* bias = (const float*)d_in[2];
    float* out = (float*)d_out;

    const int B = in_sizes[0] / SDIM;           // 1024

    fused_ntload_kernel<<<B, BLK, 0, stream>>>(z, w, bias, out);
}

// Round 9
// 93.910 us; speedup vs baseline: 1.2631x; 1.2631x over previous
//
#include <hip/hip_runtime.h>

// out[i,j] = (z[i,:] . w) * w[j] + bias[j], all f32.  S=65536, B=1024.
// Split structure (best so far, R4=102us) + row-amortized broadcast streams:
//   dot2:   2 rows/block  -> each w[i] load feeds 2 z-row FMAs (w stream halved)
//   outer4: 4 rows/block  -> each w[i]/bias[i] load feeds 4 NT row-stores
// NT stores (keep out from evicting z in L3); plain loads for z (R8 showed NT
// loads kill z's cross-replay L3 residency: 105 -> 118 us).

#define SDIM 65536
#define S4   16384     // float4 per row
#define BLK  512

typedef float floatx4 __attribute__((ext_vector_type(4)));

__device__ __forceinline__ float dot4(floatx4 a, floatx4 b) {
    return a.x * b.x + a.y * b.y + a.z * b.z + a.w * b.w;
}

// ---------------- kernel A: scal[r] = z[r,:] . w, 2 rows per block ----------
__global__ __launch_bounds__(BLK) void dot2_kernel(
    const float* __restrict__ z,
    const float* __restrict__ w,
    float* __restrict__ scal)
{
    const int r0 = blockIdx.x * 2;
    const floatx4* __restrict__ z0 =
        reinterpret_cast<const floatx4*>(z + (size_t)r0 * SDIM);
    const floatx4* __restrict__ z1 =
        reinterpret_cast<const floatx4*>(z + (size_t)(r0 + 1) * SDIM);
    const floatx4* __restrict__ w4 = reinterpret_cast<const floatx4*>(w);

    // unroll 4: per iter 4 w loads + 8 z loads (12 in flight), 8 accum chains
    float a00 = 0.f, a01 = 0.f, a02 = 0.f, a03 = 0.f;
    float a10 = 0.f, a11 = 0.f, a12 = 0.f, a13 = 0.f;
    for (int i = threadIdx.x; i < S4; i += 4 * BLK) {
        floatx4 y0 = w4[i];
        floatx4 y1 = w4[i + BLK];
        floatx4 y2 = w4[i + 2 * BLK];
        floatx4 y3 = w4[i + 3 * BLK];
        floatx4 p0 = z0[i];
        floatx4 p1 = z0[i + BLK];
        floatx4 p2 = z0[i + 2 * BLK];
        floatx4 p3 = z0[i + 3 * BLK];
        floatx4 q0 = z1[i];
        floatx4 q1 = z1[i + BLK];
        floatx4 q2 = z1[i + 2 * BLK];
        floatx4 q3 = z1[i + 3 * BLK];
        a00 += dot4(p0, y0); a01 += dot4(p1, y1);
        a02 += dot4(p2, y2); a03 += dot4(p3, y3);
        a10 += dot4(q0, y0); a11 += dot4(q1, y1);
        a12 += dot4(q2, y2); a13 += dot4(q3, y3);
    }
    float accA = (a00 + a01) + (a02 + a03);
    float accB = (a10 + a11) + (a12 + a13);

    #pragma unroll
    for (int off = 32; off > 0; off >>= 1) {
        accA += __shfl_down(accA, off, 64);
        accB += __shfl_down(accB, off, 64);
    }

    __shared__ float smem[BLK / 64][2];
    const int lane = threadIdx.x & 63;
    const int wid  = threadIdx.x >> 6;
    if (lane == 0) { smem[wid][0] = accA; smem[wid][1] = accB; }
    __syncthreads();
    if (threadIdx.x == 0) {
        float t0 = 0.f, t1 = 0.f;
        #pragma unroll
        for (int i = 0; i < BLK / 64; ++i) { t0 += smem[i][0]; t1 += smem[i][1]; }
        scal[r0]     = t0;
        scal[r0 + 1] = t1;
    }
}

// ------------- kernel B: out[r,:] = scal[r]*w + bias, 4 rows per block ------
#define OBLK   256
#define ORROWS 4
#define NCHUNK 4
#define CHUNK4 (S4 / NCHUNK)   // 4096 float4

__global__ __launch_bounds__(OBLK) void outer4_kernel(
    const float* __restrict__ scal,
    const float* __restrict__ w,
    const float* __restrict__ bias,
    float* __restrict__ out)
{
    const int group = blockIdx.x >> 2;        // row group of 4
    const int chunk = blockIdx.x & (NCHUNK - 1);
    const int r0    = group * ORROWS;
    const int base  = chunk * CHUNK4;

    const float s0 = scal[r0];
    const float s1 = scal[r0 + 1];
    const float s2 = scal[r0 + 2];
    const float s3 = scal[r0 + 3];

    const floatx4* __restrict__ w4 = reinterpret_cast<const floatx4*>(w) + base;
    const floatx4* __restrict__ b4 = reinterpret_cast<const floatx4*>(bias) + base;
    floatx4* __restrict__ o0 =
        reinterpret_cast<floatx4*>(out + (size_t)r0 * SDIM) + base;
    floatx4* __restrict__ o1 =
        reinterpret_cast<floatx4*>(out + (size_t)(r0 + 1) * SDIM) + base;
    floatx4* __restrict__ o2 =
        reinterpret_cast<floatx4*>(out + (size_t)(r0 + 2) * SDIM) + base;
    floatx4* __restrict__ o3 =
        reinterpret_cast<floatx4*>(out + (size_t)(r0 + 3) * SDIM) + base;

    // 4096 f4 / 256 thr = 16 iters; unroll 2 -> per iter 4 loads, 8 NT stores
    for (int i = threadIdx.x; i < CHUNK4; i += 2 * OBLK) {
        floatx4 y0 = w4[i];
        floatx4 y1 = w4[i + OBLK];
        floatx4 c0 = b4[i];
        floatx4 c1 = b4[i + OBLK];

        floatx4 t;
        t.x = fmaf(s0, y0.x, c0.x); t.y = fmaf(s0, y0.y, c0.y);
        t.z = fmaf(s0, y0.z, c0.z); t.w = fmaf(s0, y0.w, c0.w);
        __builtin_nontemporal_store(t, &o0[i]);
        t.x = fmaf(s1, y0.x, c0.x); t.y = fmaf(s1, y0.y, c0.y);
        t.z = fmaf(s1, y0.z, c0.z); t.w = fmaf(s1, y0.w, c0.w);
        __builtin_nontemporal_store(t, &o1[i]);
        t.x = fmaf(s2, y0.x, c0.x); t.y = fmaf(s2, y0.y, c0.y);
        t.z = fmaf(s2, y0.z, c0.z); t.w = fmaf(s2, y0.w, c0.w);
        __builtin_nontemporal_store(t, &o2[i]);
        t.x = fmaf(s3, y0.x, c0.x); t.y = fmaf(s3, y0.y, c0.y);
        t.z = fmaf(s3, y0.z, c0.z); t.w = fmaf(s3, y0.w, c0.w);
        __builtin_nontemporal_store(t, &o3[i]);

        t.x = fmaf(s0, y1.x, c1.x); t.y = fmaf(s0, y1.y, c1.y);
        t.z = fmaf(s0, y1.z, c1.z); t.w = fmaf(s0, y1.w, c1.w);
        __builtin_nontemporal_store(t, &o0[i + OBLK]);
        t.x = fmaf(s1, y1.x, c1.x); t.y = fmaf(s1, y1.y, c1.y);
        t.z = fmaf(s1, y1.z, c1.z); t.w = fmaf(s1, y1.w, c1.w);
        __builtin_nontemporal_store(t, &o1[i + OBLK]);
        t.x = fmaf(s2, y1.x, c1.x); t.y = fmaf(s2, y1.y, c1.y);
        t.z = fmaf(s2, y1.z, c1.z); t.w = fmaf(s2, y1.w, c1.w);
        __builtin_nontemporal_store(t, &o2[i + OBLK]);
        t.x = fmaf(s3, y1.x, c1.x); t.y = fmaf(s3, y1.y, c1.y);
        t.z = fmaf(s3, y1.z, c1.z); t.w = fmaf(s3, y1.w, c1.w);
        __builtin_nontemporal_store(t, &o3[i + OBLK]);
    }
}

extern "C" void kernel_launch(void* const* d_in, const int* in_sizes, int n_in,
                              void* d_out, int out_size, void* d_ws, size_t ws_size,
                              hipStream_t stream)
{
    const float* z    = (const float*)d_in[0];
    const float* w    = (const float*)d_in[1];  // (1,S,1) flat == (S,)
    const float* bias = (const float*)d_in[2];
    float* out  = (float*)d_out;
    float* scal = (float*)d_ws;                 // B floats of scratch

    const int B = in_sizes[0] / SDIM;           // 1024

    dot2_kernel<<<B / 2, BLK, 0, stream>>>(z, w, scal);
    outer4_kernel<<<(B / ORROWS) * NCHUNK, OBLK, 0, stream>>>(scal, w, bias, out);
}